// Round 2
// baseline (1163.088 us; speedup 1.0000x reference)
//
#include <hip/hip_runtime.h>

// RK4 neural-ODE: f(y) = tanh(y W1 + b1) W2 + b2;  3072 rows x 255 steps.
// Wave-synchronous, one wave per TWO rows.
//
// ROUND 6: R5 retry (R5 died on a preprocessor bug: r##R##0.xy pastes into
// the invalid token "rA0.xy" because 0.xy lexes as one pp-number; registers
// renamed rA_0 etc. so pastes are identifier+identifier).
// Theory unchanged -- latency-bound fix (R1-R4: dur pinned ~2150cy/eval vs
// ~800cy VALU floor => ~37% util; 3 chains/SIMD can't cover the ~600cy serial
// eval chain):
//  (a) TWO ROWS PER WAVE: the 128 weight VGPRs are shared between rows, so a
//      second row costs only ~40 VGPRs of state/accumulators but DOUBLES the
//      independent dependency chains (4 FMA chains in phase1, 8 in phase2,
//      2 overlapping DS round-trips). 768 blocks x 128 threads (2 waves x
//      2 rows) keeps exactly 3 blocks/CU -- no CU imbalance.
//  (b) waves_per_eu(2,2): VGPR budget 256 (est. peak ~200-220). Post-mortem
//      check: ScratchSize must stay 0.
//  (c) Output stores use all 64 lanes (low half row A, high half row B).
// Retained from R4: pre-scaled W1 (tanh via exp2), 8-way split phase 2 with
// bank-staggered h chunks (stride 20), DPP quad_perm combine + one ^32
// bpermute.

typedef float f2 __attribute__((ext_vector_type(2)));
typedef float f4 __attribute__((ext_vector_type(4)));

__device__ __forceinline__ float rl(float v, int lane) {
  return __int_as_float(__builtin_amdgcn_readlane(__float_as_int(v), lane));
}
__device__ __forceinline__ f2 fma2(f2 a, f2 b, f2 c) {
  return __builtin_elementwise_fma(a, b, c);
}
// tanh(z) with z pre-scaled by 2*log2(e): tanh = 1 - 2/(2^z + 1)
__device__ __forceinline__ float tanh_scaled(float z) {
  float t = __builtin_amdgcn_exp2f(z);
  return fmaf(-2.0f, __builtin_amdgcn_rcpf(t + 1.0f), 1.0f);
}
// quad_perm xor-1 / xor-2 (VALU-pipe cross-lane)
__device__ __forceinline__ float dpp_xor1(float x) {
  return __int_as_float(__builtin_amdgcn_update_dpp(
      0, __float_as_int(x), 0xB1, 0xF, 0xF, true));  // [1,0,3,2]
}
__device__ __forceinline__ float dpp_xor2(float x) {
  return __int_as_float(__builtin_amdgcn_update_dpp(
      0, __float_as_int(x), 0x4E, 0xF, 0xF, true));  // [2,3,0,1]
}
__device__ __forceinline__ f2 ldW2(const float* W2, int j, int d) {
  f2 r; r.x = W2[j * 32 + d]; r.y = W2[(j + 1) * 32 + d]; return r;
}
__device__ __forceinline__ float bperm(int addr, float v) {
  return __int_as_float(__builtin_amdgcn_ds_bpermute(addr, __float_as_int(v)));
}

#define REP32(X) \
  X(0) X(1) X(2) X(3) X(4) X(5) X(6) X(7) X(8) X(9) X(10) X(11) X(12) X(13) \
  X(14) X(15) X(16) X(17) X(18) X(19) X(20) X(21) X(22) X(23) X(24) X(25)   \
  X(26) X(27) X(28) X(29) X(30) X(31)

__global__ void __launch_bounds__(128)
__attribute__((amdgpu_waves_per_eu(2, 2)))
rk4_ode_kernel(const float* __restrict__ fp,   // [3072,32]
               const float* __restrict__ ts,   // [256]
               const float* __restrict__ W1,   // [32,128]
               const float* __restrict__ b1,   // [128]
               const float* __restrict__ W2,   // [128,32]
               const float* __restrict__ b2,   // [32]
               float* __restrict__ out) {      // [3072,256,32]
  // per-row h buffer: 8 chunks of 16 floats at stride 20 (bank stagger)
  // 2 waves x 2 rows = 4 buffers of 160 floats
  __shared__ float smem[4 * 160];

  const int tid = threadIdx.x;
  const int wv  = tid >> 6;                   // 0..1
  const int p   = tid & 63;
  const int rowA = blockIdx.x * 4 + wv * 2;
  const int rowB = rowA + 1;

  const int g  = (p & 3) | ((p >> 5) << 2);   // j-group: lane bits {0,1,5}
  const int j0 = g << 4;                      // 16 j's per group
  const int d0 = p & 0x1C;                    // outputs d0|m, m=0..3

  const float C = 2.885390081777926814f;      // 2*log2(e) folded into W1/b1

  // ---- W1: lane p produces h_{2p}, h_{2p+1}; packed col-pairs, pre-scaled ----
  const float2* W1v = reinterpret_cast<const float2*>(W1);
#define LOADW1(dd) f2 w1_##dd; { const float2 t_ = W1v[dd * 64 + p]; \
                                 w1_##dd.x = t_.x * C; w1_##dd.y = t_.y * C; }
  REP32(LOADW1)
#undef LOADW1
  const float2 b1t = reinterpret_cast<const float2*>(b1)[p];
  const f2 b1v = {b1t.x * C, b1t.y * C};

  // ---- W2: rows [j0, j0+16) for 4 outputs d0|m, as j-pair f2 regs ----
#define LW2(m) \
  const f2 w2_##m##_0 = ldW2(W2, j0 + 0,  d0 | m); \
  const f2 w2_##m##_1 = ldW2(W2, j0 + 2,  d0 | m); \
  const f2 w2_##m##_2 = ldW2(W2, j0 + 4,  d0 | m); \
  const f2 w2_##m##_3 = ldW2(W2, j0 + 6,  d0 | m); \
  const f2 w2_##m##_4 = ldW2(W2, j0 + 8,  d0 | m); \
  const f2 w2_##m##_5 = ldW2(W2, j0 + 10, d0 | m); \
  const f2 w2_##m##_6 = ldW2(W2, j0 + 12, d0 | m); \
  const f2 w2_##m##_7 = ldW2(W2, j0 + 14, d0 | m);
  LW2(0) LW2(1) LW2(2) LW2(3)
#undef LW2
  const float b2l = b2[p & 31];

  // ---- RK4 state: lane p holds dim d = p&31 for BOTH rows ----
  float y0A   = fp[rowA * 32 + (p & 31)];
  float y0B   = fp[rowB * 32 + (p & 31)];
  float ycurA = y0A, ycurB = y0B;
  float kaccA = 0.0f, kaccB = 0.0f;

  float* outA = out + (size_t)rowA * (256 * 32);
  float* outB = out + (size_t)rowB * (256 * 32);
  if (p < 32) outA[p] = y0A; else outB[p & 31] = y0B;

  // h LDS addressing: h_j stored at float index 20*(j>>4) + (j&15)
  float* hbA  = &smem[(wv * 2 + 0) * 160];
  float* hbB  = &smem[(wv * 2 + 1) * 160];
  float* hwrA = hbA + 20 * (p >> 3) + 2 * (p & 7);   // write f2 (j=2p,2p+1)
  float* hwrB = hbB + 20 * (p >> 3) + 2 * (p & 7);
  const f4* hrdA = reinterpret_cast<const f4*>(hbA + 20 * g); // 4x b128 reads
  const f4* hrdB = reinterpret_cast<const f4*>(hbB + 20 * g);
  const int pairaddr = (p ^ 32) << 2;

  for (int t = 0; t < 255; ++t) {
    const float dt = ts[t + 1] - ts[t];
#pragma unroll
    for (int st = 0; st < 4; ++st) {
      // ---- phase 1: z = C*(b1 + y.W1) for cols 2p,2p+1, both rows ----
      f2 aeA = b1v, aoA = {0.0f, 0.0f};
      f2 aeB = b1v, aoB = {0.0f, 0.0f};
#define P1(dd) { const float sA_ = rl(ycurA, dd); const float sB_ = rl(ycurB, dd); \
                 const f2 ssA = {sA_, sA_}; const f2 ssB = {sB_, sB_};             \
                 if ((dd) & 1) { aoA = fma2(ssA, w1_##dd, aoA);                    \
                                 aoB = fma2(ssB, w1_##dd, aoB); }                  \
                 else          { aeA = fma2(ssA, w1_##dd, aeA);                    \
                                 aeB = fma2(ssB, w1_##dd, aeB); } }
      REP32(P1)
#undef P1
      const f2 aA = aeA + aoA;
      const f2 aB = aeB + aoB;
      *reinterpret_cast<f2*>(hwrA) = (f2){tanh_scaled(aA.x), tanh_scaled(aA.y)};
      *reinterpret_cast<f2*>(hwrB) = (f2){tanh_scaled(aB.x), tanh_scaled(aB.y)};
      __builtin_amdgcn_wave_barrier();          // writes before reads

      // ---- phase 2: 16 h-floats for my j-group vs 4 output columns, 2 rows ----
      f2 accA0 = {0,0}, accA1 = {0,0}, accA2 = {0,0}, accA3 = {0,0};
      f2 accB0 = {0,0}, accB1 = {0,0}, accB2 = {0,0}, accB3 = {0,0};
      {
        const f4 rA_0 = hrdA[0], rA_1 = hrdA[1];
        const f4 rB_0 = hrdB[0], rB_1 = hrdB[1];
#define ACCA(R,m) acc##R##m = fma2(r##R##_0.xy, w2_##m##_0, acc##R##m); \
                  acc##R##m = fma2(r##R##_0.zw, w2_##m##_1, acc##R##m); \
                  acc##R##m = fma2(r##R##_1.xy, w2_##m##_2, acc##R##m); \
                  acc##R##m = fma2(r##R##_1.zw, w2_##m##_3, acc##R##m);
        ACCA(A,0) ACCA(B,0) ACCA(A,1) ACCA(B,1)
        ACCA(A,2) ACCA(B,2) ACCA(A,3) ACCA(B,3)
#undef ACCA
        const f4 rA_2 = hrdA[2], rA_3 = hrdA[3];
        const f4 rB_2 = hrdB[2], rB_3 = hrdB[3];
#define ACCB(R,m) acc##R##m = fma2(r##R##_2.xy, w2_##m##_4, acc##R##m); \
                  acc##R##m = fma2(r##R##_2.zw, w2_##m##_5, acc##R##m); \
                  acc##R##m = fma2(r##R##_3.xy, w2_##m##_6, acc##R##m); \
                  acc##R##m = fma2(r##R##_3.zw, w2_##m##_7, acc##R##m);
        ACCB(A,0) ACCB(B,0) ACCB(A,1) ACCB(B,1)
        ACCB(A,2) ACCB(B,2) ACCB(A,3) ACCB(B,3)
#undef ACCB
      }
      __builtin_amdgcn_wave_barrier();          // reads before next write

      // ---- combine group partials: ^1,^2 via DPP (VALU), select, then ^32 ----
      float kA0 = accA0.x + accA0.y, kA1 = accA1.x + accA1.y;
      float kA2 = accA2.x + accA2.y, kA3 = accA3.x + accA3.y;
      float kB0 = accB0.x + accB0.y, kB1 = accB1.x + accB1.y;
      float kB2 = accB2.x + accB2.y, kB3 = accB3.x + accB3.y;
      kA0 += dpp_xor1(kA0); kA1 += dpp_xor1(kA1);
      kA2 += dpp_xor1(kA2); kA3 += dpp_xor1(kA3);
      kB0 += dpp_xor1(kB0); kB1 += dpp_xor1(kB1);
      kB2 += dpp_xor1(kB2); kB3 += dpp_xor1(kB3);
      kA0 += dpp_xor2(kA0); kA1 += dpp_xor2(kA1);
      kA2 += dpp_xor2(kA2); kA3 += dpp_xor2(kA3);
      kB0 += dpp_xor2(kB0); kB1 += dpp_xor2(kB1);
      kB2 += dpp_xor2(kB2); kB3 += dpp_xor2(kB3);
      const float sA01 = (p & 1) ? kA1 : kA0;
      const float sA23 = (p & 1) ? kA3 : kA2;
      const float ksA  = (p & 2) ? sA23 : sA01;    // my output's quad partial
      const float sB01 = (p & 1) ? kB1 : kB0;
      const float sB23 = (p & 1) ? kB3 : kB2;
      const float ksB  = (p & 2) ? sB23 : sB01;
      const float kA = ksA + b2l + bperm(pairaddr, ksA);
      const float kB = ksB + b2l + bperm(pairaddr, ksB);

      // ---- RK4 stage combination, both rows ----
      if (st == 0) {
        kaccA = kA;                    ycurA = fmaf(0.5f * dt, kA, y0A);
        kaccB = kB;                    ycurB = fmaf(0.5f * dt, kB, y0B);
      } else if (st == 1) {
        kaccA = fmaf(2.0f, kA, kaccA); ycurA = fmaf(0.5f * dt, kA, y0A);
        kaccB = fmaf(2.0f, kB, kaccB); ycurB = fmaf(0.5f * dt, kB, y0B);
      } else if (st == 2) {
        kaccA = fmaf(2.0f, kA, kaccA); ycurA = fmaf(dt, kA, y0A);
        kaccB = fmaf(2.0f, kB, kaccB); ycurB = fmaf(dt, kB, y0B);
      } else {
        kaccA = kaccA + kA;
        y0A   = fmaf(dt * (1.0f / 6.0f), kaccA, y0A);
        ycurA = y0A;
        kaccB = kaccB + kB;
        y0B   = fmaf(dt * (1.0f / 6.0f), kaccB, y0B);
        ycurB = y0B;
      }
    }
    if (p < 32) outA[(t + 1) * 32 + p]        = y0A;
    else        outB[(t + 1) * 32 + (p & 31)] = y0B;
  }
}

extern "C" void kernel_launch(void* const* d_in, const int* in_sizes, int n_in,
                              void* d_out, int out_size, void* d_ws, size_t ws_size,
                              hipStream_t stream) {
  const float* fp = (const float*)d_in[0];   // first_point [3,1024,32]
  const float* ts = (const float*)d_in[1];   // time_steps [256]
  const float* W1 = (const float*)d_in[2];   // [32,128]
  const float* b1 = (const float*)d_in[3];   // [128]
  const float* W2 = (const float*)d_in[4];   // [128,32]
  const float* b2 = (const float*)d_in[5];   // [32]
  float* out = (float*)d_out;                // [3,1024,256,32]

  rk4_ode_kernel<<<768, 128, 0, stream>>>(fp, ts, W1, b1, W2, b2, out);
}